// Round 7
// baseline (293.092 us; speedup 1.0000x reference)
//
#include <hip/hip_runtime.h>

#define EPSF 1e-7f

constexpr int Bn = 4, Cn = 64, Kn = 19;
constexpr int HWn = 512 * 512;

// k_stats geometry: small blocks for TLP (R6 lesson: 1 block/CU serializes
// barrier-drain with compute; guide §5: compiler drains vmcnt(0) at barriers).
constexpr int SBLK    = 256;               // threads (4 waves)
constexpr int SCHUNKS = 256;               // stats chunks per image
constexpr int SPIX    = HWn / SCHUNKS;     // 1024 pixels per block
constexpr int TILE    = 64;                // pixels per LDS tile (single-buffered)
constexpr int NTILE   = SPIX / TILE;       // 16
constexpr int PSTR    = 65;                // [p][c] stride (odd -> conflict-free reads)
constexpr int PARTSZ  = 2464;              // 2432 stats + 19 counts + 13 pad

#define ALL19(M) M(0) M(1) M(2) M(3) M(4) M(5) M(6) M(7) M(8) M(9) \
                 M(10) M(11) M(12) M(13) M(14) M(15) M(16) M(17) M(18)

// ---------------- Kernel 1: per-(b,k,c) sum / sumsq / count ----------------
__global__ __launch_bounds__(SBLK, 5) void k_stats(
    const float* __restrict__ x, const int* __restrict__ gt,
    float* __restrict__ part)
{
    __shared__ float xT[TILE * PSTR];        // 16,640 B; reused as reduce scratch
    __shared__ int   scnt[4][Kn];

    const int tid  = threadIdx.x;
    const int lane = tid & 63;
    const int w    = tid >> 6;               // wave 0..3

    const int b    = blockIdx.x >> 8;
    const int pix0 = (blockIdx.x & 255) * SPIX;
    const float* xb  = x  + (size_t)b * Cn * HWn + pix0;
    const int*   gtb = gt + (size_t)b * HWn + pix0;

    // staging: q = j*256+tid -> c = q>>5 (0..63), p2 = (q&31)*2. Per wave per j:
    // 2 channels x 32 lanes x 8B contiguous. LDS write banks: 2-way (free).
    const int p2 = (tid & 31) * 2;
    const int cb = tid >> 5;
    float2 r[8];

#define LOADX(T) { _Pragma("unroll") \
    for (int j = 0; j < 8; ++j) { \
        const int c = j * 8 + cb; \
        r[j] = *reinterpret_cast<const float2*>(xb + (size_t)c * HWn + (T) * TILE + p2); \
    } }

#define WRITEX { _Pragma("unroll") \
    for (int j = 0; j < 8; ++j) { \
        const int c = j * 8 + cb; \
        xT[(p2 + 0) * PSTR + c] = r[j].x; \
        xT[(p2 + 1) * PSTR + c] = r[j].y; \
    } }

    // 19 named accumulators (R5 lesson / rule #20: arrays scratch-lower).
    // s/q are per-lane VGPRs; c counts are wave-uniform -> SGPRs.
#define DECL_(K) float s##K = 0.f, q##K = 0.f; int c##K = 0;
    ALL19(DECL_)

#define CASE_(K) { s##K += xv_; q##K = fmaf(xv_, xv_, q##K); c##K++; }
#define TREE_ { \
    if (k_ < 10) { \
      if (k_ < 5) { \
        if (k_ < 2) { if (k_ == 0) CASE_(0) else CASE_(1) } \
        else { if (k_ == 2) CASE_(2) else { if (k_ == 3) CASE_(3) else CASE_(4) } } \
      } else { \
        if (k_ < 7) { if (k_ == 5) CASE_(5) else CASE_(6) } \
        else { if (k_ == 7) CASE_(7) else { if (k_ == 8) CASE_(8) else CASE_(9) } } \
      } \
    } else { \
      if (k_ < 15) { \
        if (k_ < 12) { if (k_ == 10) CASE_(10) else CASE_(11) } \
        else { if (k_ == 12) CASE_(12) else { if (k_ == 13) CASE_(13) else CASE_(14) } } \
      } else { \
        if (k_ < 17) { if (k_ == 15) CASE_(15) else CASE_(16) } \
        else { if (k_ == 17) CASE_(17) else CASE_(18) } \
      } \
    } }

    int labC = min(max(gtb[w * 16 + (lane & 15)], 0), Kn - 1);
    int labN = 0;

    LOADX(0)

    #pragma unroll 1
    for (int t = 0; t < NTILE; ++t) {
        __syncthreads();                     // (A) xT free; drains LOADX(t)
        WRITEX                               // stage tile t
        if (t + 1 < NTILE)
            labN = min(max(gtb[(t + 1) * TILE + w * 16 + (lane & 15)], 0), Kn - 1);
        __syncthreads();                     // (B) xT ready
        if (t + 1 < NTILE) LOADX(t + 1)      // issue next loads (hide under ACCUM)

        const int pbs = (w * 16) * PSTR + lane;
        #pragma unroll 1
        for (int i = 0; i < 16; ++i) {       // wave w's 16 pixels of this tile
            const int   k_  = __builtin_amdgcn_readlane(labC, i);   // wave-uniform
            const float xv_ = xT[pbs + i * PSTR];                    // lane = channel
            TREE_
        }
        labC = labN;
    }

#define SC_(K) scnt[w][K] = c##K;
    if (lane == 0) { ALL19(SC_) }

    // cross-wave reduce: single 2432-float region in xT, 4 sequential rounds
    __syncthreads();
    float* red = xT;
#define FLW_(K) red[((K)*2+0)*64 + lane] = s##K; red[((K)*2+1)*64 + lane] = q##K;
#define FLA_(K) red[((K)*2+0)*64 + lane] += s##K; red[((K)*2+1)*64 + lane] += q##K;
    if (w == 0) { ALL19(FLW_) }
    __syncthreads();
    if (w == 1) { ALL19(FLA_) }
    __syncthreads();
    if (w == 2) { ALL19(FLA_) }
    __syncthreads();
    if (w == 3) { ALL19(FLA_) }
    __syncthreads();

    // emit partials: i = stat*1216 + c*19 + k; counts appended as floats
    float* pb = part + (size_t)blockIdx.x * PARTSZ;
    for (int i = tid; i < 2 * Cn * Kn; i += SBLK) {
        const int stat = i / (Cn * Kn);
        const int rr   = i - stat * (Cn * Kn);
        const int c = rr / Kn, k = rr - c * Kn;
        pb[i] = red[(k * 2 + stat) * 64 + c];
    }
    if (tid < Kn)
        pb[2 * Cn * Kn + tid] =
            (float)(scnt[0][tid] + scnt[1][tid] + scnt[2][tid] + scnt[3][tid]);
}

// ---------------- Kernel 2: mean/std + mixing weights -> AB table ----------------
__global__ __launch_bounds__(1024) void k_tables(
    const float* __restrict__ part, const float* __restrict__ aug,
    float* __restrict__ tabAB)
{
    __shared__ float mean_s[Kn * Cn];   // [k*64 + c]
    __shared__ float std_s [Kn * Cn];
    __shared__ float wrow  [Kn * Kn];   // [t*19 + k]
    __shared__ float wsum  [Kn];
    __shared__ float validf[Kn], cntf[Kn];

    const int b = blockIdx.x, tid = threadIdx.x;
    const float* pbase = part + (size_t)b * SCHUNKS * PARTSZ;

    if (tid < Kn) {                          // counts (stored as exact floats)
        float s = 0.f;
        for (int blk = 0; blk < SCHUNKS; ++blk)
            s += pbase[(size_t)blk * PARTSZ + 2 * Cn * Kn + tid];
        validf[tid] = (s > 0.f) ? 1.f : 0.f;
        cntf[tid]   = (s > 0.f) ? s : 1.f;
    }
    __syncthreads();

    for (int i = tid; i < Cn * Kn; i += 1024) {             // i = c*19 + k
        float s = 0.f, q = 0.f;
        for (int blk = 0; blk < SCHUNKS; ++blk) {
            s += pbase[(size_t)blk * PARTSZ + i];
            q += pbase[(size_t)blk * PARTSZ + Cn * Kn + i];
        }
        const int c = i / Kn, k = i - c * Kn;
        const float cs  = cntf[k];
        const float m   = s / cs;
        const float var = fmaxf(q / cs - m * m, 0.f);
        mean_s[k * Cn + c] = m;
        std_s [k * Cn + c] = sqrtf(var) + EPSF;
    }
    // FIX (R1): Kn*Kn = 361 -> strided loop.
    for (int i = tid; i < Kn * Kn; i += 1024) {
        const int t = i / Kn, k = i - t * Kn;
        wrow[i] = aug[((size_t)b * Kn + t) * Kn + k] * validf[k];
    }
    __syncthreads();
    if (tid < Kn) {
        float s = 0.f;
        for (int k = 0; k < Kn; ++k) s += wrow[tid * Kn + k];
        wsum[tid] = fmaxf(s, EPSF);
    }
    __syncthreads();
    for (int i = tid; i < Kn * Cn; i += 1024) {             // i = t*64 + c
        const int t = i >> 6, c = i & 63;
        const float inv = 1.f / wsum[t];
        float mm = 0.f, ms = 0.f;
        for (int k = 0; k < Kn; ++k) {
            const float wk = wrow[t * Kn + k] * inv;
            mm += wk * mean_s[k * Cn + c];
            ms += wk * std_s [k * Cn + c];
        }
        const float A  = ms / std_s[t * Cn + c];
        const float Bv = mm - mean_s[t * Cn + c] * A;
        const size_t o = ((size_t)b * Cn * Kn + c * Kn + t) * 2;  // [b][c][k][2]
        tabAB[o + 0] = A;
        tabAB[o + 1] = Bv;
    }
}

// ---------------- Kernel 3: out = x*A[gt] + B[gt] ----------------
constexpr int ABLK = 512;                  // 8 waves; 2 blocks/CU
constexpr int ACHUNKS = 128;               // chunks per image
constexpr int APIX = HWn / ACHUNKS;        // 2048 pixels per block

__global__ __launch_bounds__(ABLK, 4) void k_apply(
    const float* __restrict__ x, const int* __restrict__ gt,
    const float* __restrict__ tabAB, float* __restrict__ out)
{
    __shared__ float ABs[Cn * Kn * 2];   // [(c*19 + k)*2 + {A,B}]
    const int tid   = threadIdx.x;
    const int b     = blockIdx.x >> 7;
    const int chunk = blockIdx.x & 127;

    for (int i = tid; i < Cn * Kn * 2; i += ABLK)
        ABs[i] = tabAB[(size_t)b * Cn * Kn * 2 + i];
    __syncthreads();

    const int p0 = chunk * APIX + tid * 4;
    const int4 L = *reinterpret_cast<const int4*>(gt + (size_t)b * HWn + p0);
    const int l0 = min(max(L.x, 0), Kn - 1);
    const int l1 = min(max(L.y, 0), Kn - 1);
    const int l2 = min(max(L.z, 0), Kn - 1);
    const int l3 = min(max(L.w, 0), Kn - 1);

    const float* xp = x   + (size_t)b * Cn * HWn + p0;
    float*       op = out + (size_t)b * Cn * HWn + p0;

    #pragma unroll 8
    for (int c = 0; c < Cn; ++c) {
        const float4 v = *reinterpret_cast<const float4*>(xp + (size_t)c * HWn);
        const int co = c * Kn;
        const float2 ab0 = *reinterpret_cast<const float2*>(&ABs[(co + l0) * 2]);
        const float2 ab1 = *reinterpret_cast<const float2*>(&ABs[(co + l1) * 2]);
        const float2 ab2 = *reinterpret_cast<const float2*>(&ABs[(co + l2) * 2]);
        const float2 ab3 = *reinterpret_cast<const float2*>(&ABs[(co + l3) * 2]);
        float4 o;
        o.x = v.x * ab0.x + ab0.y;
        o.y = v.y * ab1.x + ab1.y;
        o.z = v.z * ab2.x + ab2.y;
        o.w = v.w * ab3.x + ab3.y;
        *reinterpret_cast<float4*>(op + (size_t)c * HWn) = o;
    }
}

extern "C" void kernel_launch(void* const* d_in, const int* in_sizes, int n_in,
                              void* d_out, int out_size, void* d_ws, size_t ws_size,
                              hipStream_t stream) {
    const float* x   = (const float*)d_in[0];
    const int*   gt  = (const int*)d_in[1];
    const float* aug = (const float*)d_in[2];
    float* out = (float*)d_out;

    // workspace (floats): partials | tabAB. No gcnt / memset needed anymore.
    float* part  = (float*)d_ws;                                  // 1024*2464 = 10.1 MB
    float* tabAB = part + (size_t)Bn * SCHUNKS * PARTSZ;          // 4*64*19*2

    k_stats <<<dim3(Bn * SCHUNKS), dim3(SBLK), 0, stream>>>(x, gt, part);
    k_tables<<<dim3(Bn),           dim3(1024), 0, stream>>>(part, aug, tabAB);
    k_apply <<<dim3(Bn * ACHUNKS), dim3(ABLK), 0, stream>>>(x, gt, tabAB, out);
}